// Round 8
// baseline (51.294 us; speedup 1.0000x reference)
//
#include <hip/hip_runtime.h>
#include <math.h>

// Problem dims (fixed by setup_inputs)
#define NROWS 8192   // B*T = 4*2048
#define DD    1024
#define HH    256
#define NTT   32
#define NCOLS 288    // HH + NTT
#define BM    32
#define NTHR  576    // 9 waves
#define NW    9
#define HPS   292    // HP LDS row stride (floats)

typedef __attribute__((ext_vector_type(8))) __bf16 bf16x8;
typedef __attribute__((ext_vector_type(4))) float f32x4;
typedef __attribute__((ext_vector_type(8))) unsigned short ushort8_t;

static __device__ __forceinline__ unsigned short f2bf(float f) {
    unsigned int u = __float_as_uint(f);
    unsigned int r = (u + 0x7fffu + ((u >> 16) & 1u)) >> 16;
    return (unsigned short)r;
}

static __device__ __forceinline__ float bf2f(unsigned short u) {
    return __uint_as_float(((unsigned int)u) << 16);
}

static __device__ __forceinline__ float sgnf(float x) {
    return x > 0.0f ? 1.0f : (x < 0.0f ? -1.0f : 0.0f);
}

static __device__ __forceinline__ float ternf(float x) {
    return x > 0.3f ? 1.0f : (x < -0.3f ? -1.0f : 0.0f);
}

static __device__ __forceinline__ float bspline(float u) {
    float t = fabsf(u);
    if (t < 1.0f) return 0.66666666666666663f - t * t + 0.5f * t * t * t;
    if (t < 2.0f) { float w = 2.0f - t; return 0.16666666666666666f * w * w * w; }
    return 0.0f;
}

// ---------------- K0: merged prep (grid 288), NO atomics ----------------
__global__ __launch_bounds__(256) void k_prep(const float* __restrict__ W1,
                                              const float* __restrict__ dirs,
                                              const float* __restrict__ gamma,
                                              const float* __restrict__ beta,
                                              unsigned short* __restrict__ WT,
                                              float* __restrict__ colsumP,
                                              float* __restrict__ bwP) {
    int bid = blockIdx.x;
    int tid = threadIdx.x;
    if (bid < 256) {
        __shared__ float tile[32][33];
        __shared__ float redg[8][32];
        __shared__ float redb[8][32];
        int ktile = bid & 31;            // d tiles of 32
        int ntile = bid >> 5;            // j tiles of 32
        int tx = tid & 31;
        int ty = tid >> 5;               // 0..7
        float sg = 0.f, sb = 0.f;
#pragma unroll
        for (int i = 0; i < 4; ++i) {
            int k = ktile * 32 + ty + i * 8;
            int n = ntile * 32 + tx;
            float w = W1[(size_t)k * HH + n];        // coalesced over n
            float gk = gamma[k];
            tile[ty + i * 8][tx] = w * gk;
            sg += w * gk;
            sb += w * beta[k];
        }
        redg[ty][tx] = sg;
        redb[ty][tx] = sb;
        __syncthreads();
#pragma unroll
        for (int i = 0; i < 4; ++i) {
            int n = ntile * 32 + ty + i * 8;
            int k = ktile * 32 + tx;
            WT[(size_t)n * DD + k] = f2bf(tile[tx][ty + i * 8]);  // coalesced over k
        }
        if (ty == 0) {
            float a = 0.f, c = 0.f;
#pragma unroll
            for (int k = 0; k < 8; ++k) { a += redg[k][tx]; c += redb[k][tx]; }
            int j = ntile * 32 + tx;
            colsumP[ktile * NCOLS + j] = a;
            bwP[ktile * NCOLS + j]     = c;
        }
    } else {
        int r = bid - 256;               // 0..31
        float4 v  = ((const float4*)(dirs + (size_t)r * DD))[tid];
        float4 g  = ((const float4*)gamma)[tid];
        float4 be = ((const float4*)beta)[tid];
        float s0 = sgnf(v.x), s1 = sgnf(v.y), s2 = sgnf(v.z), s3 = sgnf(v.w);
        ushort4 o;
        o.x = f2bf(s0 * g.x); o.y = f2bf(s1 * g.y);
        o.z = f2bf(s2 * g.z); o.w = f2bf(s3 * g.w);
        ((ushort4*)(WT + (size_t)(HH + r) * DD))[tid] = o;
        float ps = s0 * g.x + s1 * g.y + s2 * g.z + s3 * g.w;
        float pb = s0 * be.x + s1 * be.y + s2 * be.z + s3 * be.w;
#pragma unroll
        for (int off = 32; off; off >>= 1) {
            ps += __shfl_xor(ps, off);
            pb += __shfl_xor(pb, off);
        }
        __shared__ float red[8];
        int wid = tid >> 6, lane = tid & 63;
        if (lane == 0) { red[wid] = ps; red[wid + 4] = pb; }
        if (tid < 31) {                  // zero partial slots k=1..31
            colsumP[(tid + 1) * NCOLS + HH + r] = 0.f;
            bwP[(tid + 1) * NCOLS + HH + r]     = 0.f;
        }
        __syncthreads();
        if (tid == 0) {
            colsumP[HH + r] = red[0] + red[1] + red[2] + red[3];
            bwP[HH + r]     = red[4] + red[5] + red[6] + red[7];
        }
    }
}

// ---------------- K1: fused LN-GEMM + epilogue, BARRIER-FREE K-loop ----------
// 256 blocks (1/CU), 576 threads (9 waves). Phase 1: waves 0-7 stage the whole
// 32x1024 x-tile into Xl (bf16, swizzled) with inline LN stats; wave 8 reduces
// colsum/bw partials. ONE barrier. Phase 2: K-loop with NO barriers — B frags
// loaded per-wave straight from L2-resident WT into VGPRs, A frags via
// ds_read from persistent Xl; compiler pipelines freely, 9 waves overlap.
// Phase 3: one barrier, LN-corrected HP -> LDS, per-row epilogue.
__global__ __launch_bounds__(NTHR) void k_fused(
    const float* __restrict__ x, const unsigned short* __restrict__ WT,
    const float* __restrict__ colsumP, const float* __restrict__ bwP,
    const float* __restrict__ positions, const int* __restrict__ states,
    const float* __restrict__ b1, const float* __restrict__ W2,
    const float* __restrict__ b2, const float* __restrict__ spc,
    const float* __restrict__ sps, const float* __restrict__ dirs,
    const float* __restrict__ ssig, const float* __restrict__ semb,
    const float* __restrict__ smod, const float* __restrict__ oscale,
    float* __restrict__ out) {
    __shared__ short Xl[BM * DD];           // 64 KB persistent bf16 x tile
    __shared__ float HPl[BM * HPS];         // 36.5 KB
    __shared__ float stats[BM][2];
    __shared__ float Csum_l[NCOLS];
    __shared__ float Bw_l[NCOLS];

    int tid  = threadIdx.x;
    int row0 = blockIdx.x * BM;
    int lane = tid & 63;
    int wid  = tid >> 6;                    // 0..8
    int wn = wid;                           // wave col group (32 cols)
    int l15 = lane & 15, l4 = lane >> 4;

    // ---- Phase 1: stage x-tile (waves 0-7) | reduce colsum partials (wave 8)
    if (wid == 8) {
        for (int j = lane; j < NCOLS; j += 64) {
            float a = 0.f, c = 0.f;
#pragma unroll 8
            for (int k = 0; k < 32; ++k) {
                a += colsumP[k * NCOLS + j];
                c += bwP[k * NCOLS + j];
            }
            Csum_l[j] = a;
            Bw_l[j]   = c;
        }
    } else {
        int sr = tid >> 4;                  // 0..31
        int sc = tid & 15;                  // 16 threads/row, 64 floats each
        const float4* xsrc = (const float4*)(x + (size_t)(row0 + sr) * DD + sc * 64);
        int swz = (sr & 7) << 4;
        char* xdst = (char*)Xl + sr * 2048;
        float s = 0.f, sq = 0.f;
#pragma unroll
        for (int q = 0; q < 8; ++q) {
            float4 v0 = xsrc[q * 2];
            float4 v1 = xsrc[q * 2 + 1];
            s  += (v0.x + v0.y + v0.z + v0.w) + (v1.x + v1.y + v1.z + v1.w);
            sq += (v0.x*v0.x + v0.y*v0.y + v0.z*v0.z + v0.w*v0.w)
                + (v1.x*v1.x + v1.y*v1.y + v1.z*v1.z + v1.w*v1.w);
            ushort8_t w;
            w[0] = f2bf(v0.x); w[1] = f2bf(v0.y); w[2] = f2bf(v0.z); w[3] = f2bf(v0.w);
            w[4] = f2bf(v1.x); w[5] = f2bf(v1.y); w[6] = f2bf(v1.z); w[7] = f2bf(v1.w);
            *(ushort8_t*)(xdst + ((sc * 128 + q * 16) ^ swz)) = w;
        }
        // reduce over the 16 staging threads of this row (contiguous lanes)
        s  += __shfl_xor(s, 1);  s  += __shfl_xor(s, 2);
        s  += __shfl_xor(s, 4);  s  += __shfl_xor(s, 8);
        sq += __shfl_xor(sq, 1); sq += __shfl_xor(sq, 2);
        sq += __shfl_xor(sq, 4); sq += __shfl_xor(sq, 8);
        if (sc == 0) {
            float mu  = s * (1.0f / DD);
            float var = sq * (1.0f / DD) - mu * mu;
            stats[sr][0] = mu;
            stats[sr][1] = rsqrtf(var + 1e-5f);
        }
    }
    __syncthreads();

    // ---- Phase 2: barrier-free K-loop ----
    // B frags straight from WT (L2-resident): col = wn*32 + nf*16 + l15.
    const unsigned short* bp0 = WT + (size_t)(wn * 32 + l15) * DD + l4 * 8;
    const unsigned short* bp1 = bp0 + (size_t)16 * DD;
    int raby0 = l15 * 2048;
    int raby1 = (16 + l15) * 2048;
    int sw = (l15 & 7) << 4;                // rows l15 and 16+l15 share (r&7)

    f32x4 acc[2][2];
#pragma unroll
    for (int i = 0; i < 2; ++i)
#pragma unroll
        for (int j = 0; j < 2; ++j) acc[i][j] = (f32x4){0.f, 0.f, 0.f, 0.f};

#pragma unroll 8
    for (int kt = 0; kt < 16; ++kt) {
#pragma unroll
        for (int ks = 0; ks < 2; ++ks) {
            int cbyte = kt * 128 + ((ks * 64 + l4 * 16) ^ sw);
            bf16x8 a0 = *(const bf16x8*)((const char*)Xl + raby0 + cbyte);
            bf16x8 a1 = *(const bf16x8*)((const char*)Xl + raby1 + cbyte);
            int eoff = kt * 64 + ks * 32;
            bf16x8 b0 = *(const bf16x8*)(bp0 + eoff);
            bf16x8 b1 = *(const bf16x8*)(bp1 + eoff);
            acc[0][0] = __builtin_amdgcn_mfma_f32_16x16x32_bf16(a0, b0, acc[0][0], 0, 0, 0);
            acc[0][1] = __builtin_amdgcn_mfma_f32_16x16x32_bf16(a0, b1, acc[0][1], 0, 0, 0);
            acc[1][0] = __builtin_amdgcn_mfma_f32_16x16x32_bf16(a1, b0, acc[1][0], 0, 0, 0);
            acc[1][1] = __builtin_amdgcn_mfma_f32_16x16x32_bf16(a1, b1, acc[1][1], 0, 0, 0);
        }
    }

    // LN-corrected tile -> HPl (D frag: col=lane&15, row=(lane>>4)*4+i)
#pragma unroll
    for (int mf = 0; mf < 2; ++mf) {
#pragma unroll
        for (int nf = 0; nf < 2; ++nf) {
            int colg = wn * 32 + nf * 16 + l15;
            float cs = Csum_l[colg];
            float bw = Bw_l[colg];
            int r0 = mf * 16 + l4 * 4;
#pragma unroll
            for (int i = 0; i < 4; ++i) {
                float mu = stats[r0 + i][0], rs = stats[r0 + i][1];
                HPl[(r0 + i) * HPS + colg] = rs * acc[mf][nf][i] - mu * rs * cs + bw;
            }
        }
    }
    __syncthreads();

    // ---- Phase 3: per-row epilogue; wave w handles rows w, w+9, w+18, w+27 ----
    float4 b1v = ((const float4*)b1)[lane];
    float w2a[4], w2b[4];
#pragma unroll
    for (int i = 0; i < 4; ++i) {
        int j = lane * 4 + i;
        w2a[i] = W2[2 * j];
        w2b[i] = W2[2 * j + 1];
    }
    float tvs[2] = {0.f, 0.f};
    if (lane < NTT) {
#pragma unroll
        for (int s2 = 0; s2 < 2; ++s2) {
            float d0 = 0.f;
#pragma unroll
            for (int k = 0; k < 8; ++k) d0 += semb[s2 * 8 + k] * ssig[lane * 8 + k];
            tvs[s2] = 1.0f / (1.0f + expf(-d0));
        }
    }
    float osc = oscale[0];
    float bb0 = b2[0], bb1 = b2[1];

    for (int r = wid; r < BM; r += NW) {
        int row = row0 + r;
        float4 hv = *(const float4*)&HPl[r * HPS + lane * 4];
        float hs[4] = {hv.x, hv.y, hv.z, hv.w};
        float bs[4] = {b1v.x, b1v.y, b1v.z, b1v.w};
        float sa = 0.f, sb2 = 0.f;
#pragma unroll
        for (int i = 0; i < 4; ++i) {
            float h = hs[i] + bs[i];
            float g = 0.5f * h * (1.0f + erff(h * 0.70710678118654752f));
            sa  += g * w2a[i];
            sb2 += g * w2b[i];
        }
#pragma unroll
        for (int off = 32; off; off >>= 1) {
            sa  += __shfl_xor(sa, off);
            sb2 += __shfl_xor(sb2, off);
        }
        float av2 = tanhf(sa + bb0);
        float bv2 = tanhf(sb2 + bb1);

        int st = states[row];
        float comb;
        if (lane < NTT) {
            float content = HPl[r * HPS + HH + lane];
            float pn = positions[row] * ((float)NTT / 2048.0f);
            float spv = bspline((pn - (float)lane) * 0.5f);
            comb = content * spv * tvs[st];
        } else {
            comb = -__builtin_inff();
        }
        int bi = lane;
#pragma unroll
        for (int off = 32; off; off >>= 1) {
            float ov = __shfl_xor(comb, off);
            int   oi = __shfl_xor(bi, off);
            if (ov > comb || (ov == comb && oi < bi)) { comb = ov; bi = oi; }
        }
        int ia = (int)((av2 + 1.0f) * 8.0f); ia = ia < 0 ? 0 : (ia > 15 ? 15 : ia);
        int ib = (int)((bv2 + 1.0f) * 8.0f); ib = ib < 0 ? 0 : (ib > 15 ? 15 : ib);
        const float* cc = spc + (((size_t)bi * 16 + ia) * 16 + ib) * 3;
        float c0 = ternf(cc[0]), c1 = ternf(cc[1]), c2 = ternf(cc[2]);
        float la = (av2 + 1.0f - (float)ia * 0.125f) * 8.0f;
        float lb = (bv2 + 1.0f - (float)ib * 0.125f) * 8.0f;
        float scale = (c0 + c1 * la + c2 * lb) * sps[bi];
        float cr = scale * smod[st * NTT + bi] * osc;

        // x from LDS (bf16), dir from global; out = x + cr*dir
        // idx indexes 4-float (= 4-bf16 = 8-byte) chunks; swizzle bits 4-6
        // commute with the 8-byte-aligned offset (staged in 16B units).
        int swzr = (r & 7) << 4;
        const float4* dr = (const float4*)(dirs + (size_t)bi * DD);
        float4* orow = (float4*)(out + (size_t)row * DD);
#pragma unroll
        for (int i = 0; i < 4; ++i) {
            int idx = i * 64 + lane;                  // float4 index in row
            int byteoff = r * 2048 + ((idx * 8) ^ swzr);
            ushort4 xv = *(const ushort4*)((const char*)Xl + byteoff);
            float4 dv = dr[idx];
            float4 o;
            o.x = fmaf(cr, dv.x, bf2f(xv.x));
            o.y = fmaf(cr, dv.y, bf2f(xv.y));
            o.z = fmaf(cr, dv.z, bf2f(xv.z));
            o.w = fmaf(cr, dv.w, bf2f(xv.w));
            orow[idx] = o;
        }
    }
}

extern "C" void kernel_launch(void* const* d_in, const int* in_sizes, int n_in,
                              void* d_out, int out_size, void* d_ws, size_t ws_size,
                              hipStream_t stream) {
    const float* x     = (const float*)d_in[0];
    const float* pos   = (const float*)d_in[1];
    const int*   st    = (const int*)d_in[2];
    const float* gam   = (const float*)d_in[3];
    const float* bet   = (const float*)d_in[4];
    const float* W1    = (const float*)d_in[5];
    const float* b1    = (const float*)d_in[6];
    const float* W2    = (const float*)d_in[7];
    const float* b2    = (const float*)d_in[8];
    const float* spc   = (const float*)d_in[9];
    const float* sps   = (const float*)d_in[10];
    const float* dirs  = (const float*)d_in[11];
    const float* ssig  = (const float*)d_in[12];
    const float* semb  = (const float*)d_in[13];
    const float* smod  = (const float*)d_in[14];
    const float* oscal = (const float*)d_in[15];
    float* out = (float*)d_out;

    char* ws = (char*)d_ws;
    unsigned short* WT = (unsigned short*)ws;                  // 288*1024 bf16 = 576 KiB
    float* colsumP = (float*)(ws + 589824);                    // 32*288 f32 = 36 KiB
    float* bwP     = (float*)(ws + 589824 + 36864);            // 32*288 f32

    k_prep<<<288, 256, 0, stream>>>(W1, dirs, gam, bet, WT, colsumP, bwP);
    k_fused<<<NROWS / BM, NTHR, 0, stream>>>(x, WT, colsumP, bwP, pos, st, b1, W2, b2,
                                             spc, sps, dirs, ssig, semb, smod, oscal, out);
}